// Round 12
// baseline (337.652 us; speedup 1.0000x reference)
//
#include <hip/hip_runtime.h>

#define DIM 128
#define NBLK 256        // edge-partition blocks for hist/scatter (must match)
#define BKT_BITS 9      // 512 rows per bucket
#define BKT_ROWS 512
#define MAXBUK 1024     // supports n up to 512K rows

#define S8   4096.0f            // fp8 table scale (2^12, exact)
#define INV8 (1.0f / 4096.0f)

using f16 = _Float16;
using f16x4 = __attribute__((ext_vector_type(4))) f16;
using f32x4 = __attribute__((ext_vector_type(4))) float;
using f32x2 = __attribute__((ext_vector_type(2))) float;

// ---------------- CSR build: atomic-free counting sort ----------------
// History: direct scatter = 16x write amplification (rounds 3-4). Global-atomic
// binning = atomic-latency-bound (rounds 5-6, ~5 atomics/us). This build has
// ZERO global atomics: positions precomputed by scans; stores fire-and-forget
// and temporally clustered per (block,bucket). Round 7: 379 us total.

// same-XCD blocks get adjacent output sub-ranges inside each bucket, so
// range-boundary cache lines are shared only within one XCD's L2
__device__ __forceinline__ int permb(int b) { return ((b & 7) << 5) | (b >> 3); }

// pass 1: per-block LDS histogram over 512-row buckets (both edge endpoints)
__global__ __launch_bounds__(256) void k_hist(const int* __restrict__ u_idx,
                                              const int* __restrict__ i_idx,
                                              int E, int n_u, int NBUK,
                                              int* __restrict__ hist) {
    __shared__ int h[MAXBUK];
    int b = blockIdx.x, tid = threadIdx.x;
    for (int j = tid; j < NBUK; j += 256) h[j] = 0;
    __syncthreads();
    int chunk = (E + NBLK - 1) / NBLK;
    int i0 = b * chunk, i1 = E < i0 + chunk ? E : i0 + chunk;
    for (int i = i0 + tid; i < i1; i += 256) {
        int u = __builtin_nontemporal_load(&u_idx[i]);
        int t = __builtin_nontemporal_load(&i_idx[i]) + n_u;
        atomicAdd(&h[u >> BKT_BITS], 1);
        atomicAdd(&h[t >> BKT_BITS], 1);
    }
    __syncthreads();
    int pb = permb(b);
    for (int j = tid; j < NBUK; j += 256) hist[j * NBLK + pb] = h[j];
}

// pass 2a: per-bucket exclusive scan over the 256 block counts (in place);
// bucket total goes to bb[k]
__global__ __launch_bounds__(256) void k_scanB(int* __restrict__ hist,
                                               int* __restrict__ bb) {
    __shared__ int sh[256];
    int k = blockIdx.x, t = threadIdx.x;
    int v = hist[k * NBLK + t];
    sh[t] = v;
    __syncthreads();
    for (int off = 1; off < 256; off <<= 1) {
        int tmp = (t >= off) ? sh[t - off] : 0;
        __syncthreads();
        sh[t] += tmp;
        __syncthreads();
    }
    hist[k * NBLK + t] = sh[t] - v;  // exclusive over (permuted) blocks
    if (t == 255) bb[k] = sh[255];   // bucket total
}

// pass 2b: exclusive scan of bucket totals -> bucket bases; bb[NBUK] = 2E
__global__ __launch_bounds__(1024) void k_scanT(int* __restrict__ bb, int NBUK) {
    __shared__ int sh[1024];
    int t = threadIdx.x;
    int v = (t < NBUK) ? bb[t] : 0;
    sh[t] = v;
    __syncthreads();
    for (int off = 1; off < 1024; off <<= 1) {
        int tmp = (t >= off) ? sh[t - off] : 0;
        __syncthreads();
        sh[t] += tmp;
        __syncthreads();
    }
    if (t < NBUK) bb[t] = sh[t] - v;
    if (t == NBUK - 1) bb[NBUK] = sh[t];
}

// pass 3: deterministic scatter into bucket-major pre[]. Entry = (c<<9 | r&511)
// (c < 2^19 ok for n=300K). Only LDS atomics (intra-block ranking); each
// (block,bucket) range ~80 B written back-to-back -> L2 write-combining.
__global__ __launch_bounds__(256) void k_scatter(const int* __restrict__ u_idx,
                                                 const int* __restrict__ i_idx,
                                                 int E, int n_u, int NBUK,
                                                 const int* __restrict__ hist,
                                                 const int* __restrict__ bb,
                                                 unsigned* __restrict__ pre) {
    __shared__ int boff[MAXBUK];
    __shared__ int cnt[MAXBUK];
    int b = blockIdx.x, tid = threadIdx.x;
    int pb = permb(b);
    for (int j = tid; j < NBUK; j += 256) {
        boff[j] = bb[j] + hist[j * NBLK + pb];
        cnt[j] = 0;
    }
    __syncthreads();
    int chunk = (E + NBLK - 1) / NBLK;
    int i0 = b * chunk, i1 = E < i0 + chunk ? E : i0 + chunk;
    for (int i = i0 + tid; i < i1; i += 256) {
        int u = __builtin_nontemporal_load(&u_idx[i]);
        int t = __builtin_nontemporal_load(&i_idx[i]) + n_u;
        int ku = u >> BKT_BITS, kt = t >> BKT_BITS;
        int p1 = atomicAdd(&cnt[ku], 1);
        pre[boff[ku] + p1] = ((unsigned)t << BKT_BITS) | (unsigned)(u & (BKT_ROWS - 1));
        int p2 = atomicAdd(&cnt[kt], 1);
        pre[boff[kt] + p2] = ((unsigned)u << BKT_BITS) | (unsigned)(t & (BKT_ROWS - 1));
    }
}

// pass 4: one block per bucket. Builds row_ptr + rnorm for its 512 rows from
// the bucket's own entries (LDS histogram + pair-scan), places into the
// bucket's contiguous ~20KB adj span (single-XCD L2-hot), encodes the fp8
// gather table xq0[v] = fp8(S8*rnorm[v]*x0[v]), and emits a DEGREE-SORTED
// row permutation (bucket-local counting sort). SpMM waves process rows in
// perm order, so the two half-waves of each wave get near-equal degrees —
// kills the ~15-20% exec-mask waste from max(degA,degB) loop divergence.
// Per-row arithmetic is untouched (bitwise-identical output).
__global__ __launch_bounds__(256) void k_place(const int* __restrict__ bb, int n, int n_u,
                                               const unsigned* __restrict__ pre,
                                               const float* __restrict__ u_emb,
                                               const float* __restrict__ i_emb,
                                               int* __restrict__ row_ptr,
                                               float* __restrict__ rnorm,
                                               int* __restrict__ adj,
                                               unsigned* __restrict__ xq0,
                                               int* __restrict__ perm) {
    __shared__ int cnt[BKT_ROWS];
    __shared__ int cur[BKT_ROWS];
    __shared__ int ps[256];
    __shared__ int dh[256];
    int b = blockIdx.x, t = threadIdx.x;
    int r0 = b << BKT_BITS;
    int base = bb[b], end = bb[b + 1];
    cnt[t] = 0;
    cnt[t + 256] = 0;
    __syncthreads();
    for (int i = base + t; i < end; i += 256)
        atomicAdd(&cnt[pre[i] & (BKT_ROWS - 1)], 1);
    __syncthreads();
    // exclusive scan over 512 rows via pair-sums (256-wide Hillis-Steele)
    int a0 = cnt[2 * t], a1 = cnt[2 * t + 1];
    int pv = a0 + a1;
    ps[t] = pv;
    __syncthreads();
    for (int off = 1; off < 256; off <<= 1) {
        int tmp = (t >= off) ? ps[t - off] : 0;
        __syncthreads();
        ps[t] += tmp;
        __syncthreads();
    }
    int ex = ps[t] - pv;        // elems before row 2t
    int e0 = base + ex;         // start of row 2t
    int e1 = e0 + a0;           // start of row 2t+1
    cur[2 * t] = e0;
    cur[2 * t + 1] = e1;
    int rows = n - r0; if (rows > BKT_ROWS) rows = BKT_ROWS;
    if (2 * t < rows) {
        row_ptr[r0 + 2 * t] = e0;
        rnorm[r0 + 2 * t] = (a0 > 0) ? rsqrtf(2.0f * (float)a0) : 0.0f;
    }
    if (2 * t + 1 < rows) {
        row_ptr[r0 + 2 * t + 1] = e1;
        rnorm[r0 + 2 * t + 1] = (a1 > 0) ? rsqrtf(2.0f * (float)a1) : 0.0f;
    }
    if (t == 0 && r0 + BKT_ROWS >= n) row_ptr[n] = end;
    __syncthreads();
    for (int i = base + t; i < end; i += 256) {
        unsigned p = pre[i];  // L2-hot from k_scatter
        int rl = (int)(p & (BKT_ROWS - 1));
        int c = (int)(p >> BKT_BITS);
        int pos = atomicAdd(&cur[rl], 1);
        adj[pos] = c;
    }
    // ---- degree-sort epilogue: bucket-local counting sort -> perm ----
    dh[t] = 0;
    __syncthreads();
    for (int rl = t; rl < rows; rl += 256) {
        int d = cnt[rl]; if (d > 255) d = 255;
        atomicAdd(&dh[d], 1);
    }
    __syncthreads();
    int dv = dh[t];
    ps[t] = dv;
    __syncthreads();
    for (int off = 1; off < 256; off <<= 1) {
        int tmp = (t >= off) ? ps[t - off] : 0;
        __syncthreads();
        ps[t] += tmp;
        __syncthreads();
    }
    dh[t] = ps[t] - dv;  // exclusive base per degree bin (running cursor)
    __syncthreads();
    for (int rl = t; rl < rows; rl += 256) {
        int d = cnt[rl]; if (d > 255) d = 255;
        int pos = atomicAdd(&dh[d], 1);
        perm[r0 + pos] = r0 + rl;
    }
    // ---- fused fp8-encode epilogue (cnt[] untouched since histogram) ----
    for (int g = t; g < rows * 32; g += 256) {
        int vr = g >> 5;
        int lane = g & 31;
        int v = r0 + vr;
        int d = cnt[vr];
        float r = (d > 0) ? rsqrtf(2.0f * (float)d) : 0.0f;
        float sr = r * S8;
        const float* src = (v < n_u) ? (u_emb + (size_t)v * DIM)
                                     : (i_emb + (size_t)(v - n_u) * DIM);
        f32x4 x = __builtin_nontemporal_load(
            reinterpret_cast<const f32x4*>(src + lane * 4));
        int q = __builtin_amdgcn_cvt_pk_fp8_f32(x[0] * sr, x[1] * sr, 0, false);
        q = __builtin_amdgcn_cvt_pk_fp8_f32(x[2] * sr, x[3] * sr, q, true);
        xq0[(size_t)v * 32 + lane] = (unsigned)q;
    }
}

// ---------------- SpMM ----------------
// One 32-lane half-wave per row (row = perm[idx], degree-sorted so wave
// halves have near-equal loop counts); 4 fp8 elements (4B uint) per lane.
// Gather tables are fp8, pre-scaled by S8*rnorm[c] (weights folded).
// 8-wide issue block (r11): all 8 gathers in flight before any decode.
// MODE 0: gathers xq0; acc = S8 * x1[row]/rnorm[row]. Writes:
//   xq1[row] = fp8(rnr^2 * acc),  p01[row] = fp16(x0 + rnr*acc/S8).
// MODE 1: gathers xq1; out = (p01[row] + rnr*acc/S8) / 3.  y store NT.

#define DECODE_ACC(Q)                                                     \
    {                                                                     \
        f32x2 lo_ = __builtin_amdgcn_cvt_pk_f32_fp8((int)(Q), false);     \
        f32x2 hi_ = __builtin_amdgcn_cvt_pk_f32_fp8((int)(Q), true);      \
        acc[0] += lo_[0]; acc[1] += lo_[1];                               \
        acc[2] += hi_[0]; acc[3] += hi_[1];                               \
    }

template <int MODE>
__global__ __launch_bounds__(256) void k_spmm(const int* __restrict__ row_ptr,
                                              const int* __restrict__ adj,
                                              const float* __restrict__ rnorm,
                                              const int* __restrict__ perm,
                                              const unsigned* __restrict__ xq,
                                              const f16* __restrict__ p01,
                                              const float* __restrict__ u_emb,
                                              const float* __restrict__ i_emb,
                                              int n_u, int n,
                                              float* __restrict__ y,
                                              unsigned* __restrict__ xq1o,
                                              f16* __restrict__ p01o) {
    int g = blockIdx.x * blockDim.x + threadIdx.x;
    int ridx = g >> 5;
    int lane = g & 31;
    if (ridx >= n) return;
    int row = perm[ridx];
    int s = row_ptr[row];
    int e = row_ptr[row + 1];
    float rnr = rnorm[row];

    // hoisted epilogue stream loads (latency hides under the gather loop)
    f32x4 x0;
    f16x4 p;
    if (MODE == 0) {
        const float* x0b = (row < n_u) ? (u_emb + (size_t)row * DIM)
                                       : (i_emb + (size_t)(row - n_u) * DIM);
        x0 = __builtin_nontemporal_load(
            reinterpret_cast<const f32x4*>(x0b + lane * 4));
    } else {
        p = __builtin_nontemporal_load(
            reinterpret_cast<const f16x4*>(p01 + (size_t)row * DIM + lane * 4));
    }

    f32x4 acc = {0.f, 0.f, 0.f, 0.f};
    const unsigned* xb = xq + lane;
    int k = s;
    // 8-wide issue block: all 8 gathers in flight before any decode
    for (; k + 8 <= e; k += 8) {
        int c0 = adj[k + 0], c1 = adj[k + 1], c2 = adj[k + 2], c3 = adj[k + 3];
        int c4 = adj[k + 4], c5 = adj[k + 5], c6 = adj[k + 6], c7 = adj[k + 7];
        unsigned q0 = xb[(size_t)c0 * 32];
        unsigned q1 = xb[(size_t)c1 * 32];
        unsigned q2 = xb[(size_t)c2 * 32];
        unsigned q3 = xb[(size_t)c3 * 32];
        unsigned q4 = xb[(size_t)c4 * 32];
        unsigned q5 = xb[(size_t)c5 * 32];
        unsigned q6 = xb[(size_t)c6 * 32];
        unsigned q7 = xb[(size_t)c7 * 32];
        DECODE_ACC(q0) DECODE_ACC(q1) DECODE_ACC(q2) DECODE_ACC(q3)
        DECODE_ACC(q4) DECODE_ACC(q5) DECODE_ACC(q6) DECODE_ACC(q7)
    }
    // 4-wide block
    if (k + 4 <= e) {
        int c0 = adj[k + 0], c1 = adj[k + 1], c2 = adj[k + 2], c3 = adj[k + 3];
        unsigned q0 = xb[(size_t)c0 * 32];
        unsigned q1 = xb[(size_t)c1 * 32];
        unsigned q2 = xb[(size_t)c2 * 32];
        unsigned q3 = xb[(size_t)c3 * 32];
        DECODE_ACC(q0) DECODE_ACC(q1) DECODE_ACC(q2) DECODE_ACC(q3)
        k += 4;
    }
    // scalar tail (0-3)
    for (; k < e; ++k) {
        int c = adj[k];
        unsigned q = xb[(size_t)c * 32];
        DECODE_ACC(q)
    }

    if (MODE == 0) {
        // layer-2 gather table: fp8(S8 * rnorm * x1) = fp8(rnr^2 * acc)
        float sc = rnr * rnr;
        int q = __builtin_amdgcn_cvt_pk_fp8_f32(acc[0] * sc, acc[1] * sc, 0, false);
        q = __builtin_amdgcn_cvt_pk_fp8_f32(acc[2] * sc, acc[3] * sc, q, true);
        xq1o[(size_t)row * 32 + lane] = (unsigned)q;
        // epilogue operand: fp16(x0 + x1), exact x0 from emb (hoisted load)
        float t1 = rnr * INV8;  // x1 = acc * rnr / S8
        f16x4 po;
        po[0] = (f16)(x0[0] + acc[0] * t1);
        po[1] = (f16)(x0[1] + acc[1] * t1);
        po[2] = (f16)(x0[2] + acc[2] * t1);
        po[3] = (f16)(x0[3] + acc[3] * t1);
        *reinterpret_cast<f16x4*>(p01o + (size_t)row * DIM + lane * 4) = po;
    } else {
        const float third = 1.0f / 3.0f;
        float t2 = rnr * INV8;  // x2 = acc * rnr / S8
        f32x4 o;
        o[0] = ((float)p[0] + acc[0] * t2) * third;
        o[1] = ((float)p[1] + acc[1] * t2) * third;
        o[2] = ((float)p[2] + acc[2] * t2) * third;
        o[3] = ((float)p[3] + acc[3] * t2) * third;
        __builtin_nontemporal_store(
            o, reinterpret_cast<f32x4*>(y + (size_t)row * DIM + lane * 4));
    }
}

// ---------------- host ----------------

extern "C" void kernel_launch(void* const* d_in, const int* in_sizes, int n_in,
                              void* d_out, int out_size, void* d_ws, size_t ws_size,
                              hipStream_t stream) {
    const float* u_emb = (const float*)d_in[0];
    const float* i_emb = (const float*)d_in[1];
    const int* u_idx = (const int*)d_in[2];
    const int* i_idx = (const int*)d_in[3];

    const int n_u = in_sizes[0] / DIM;
    const int n_i = in_sizes[1] / DIM;
    const int n = n_u + n_i;
    const int E = in_sizes[2];
    const int twoE = 2 * E;
    const int NBUK = (n + BKT_ROWS - 1) >> BKT_BITS;  // <= MAXBUK for n <= 512K

    // workspace layout
    char* w = (char*)d_ws;
    auto alloc = [&](size_t bytes) -> void* {
        void* p = (void*)w;
        w += (bytes + 255) & ~(size_t)255;
        return p;
    };
    unsigned* xq0   = (unsigned*)alloc((size_t)n * 32 * sizeof(unsigned)); // fp8 S*rnorm*x0
    unsigned* xq1   = (unsigned*)alloc((size_t)n * 32 * sizeof(unsigned)); // fp8 S*rnorm*x1
    f16*   p01     = (f16*)alloc((size_t)n * DIM * sizeof(f16));          // fp16 x0+x1
    float* rnorm   = (float*)alloc((size_t)n * sizeof(float));
    int*   row_ptr = (int*)alloc((size_t)(n + 1) * sizeof(int));
    int*   adj     = (int*)alloc((size_t)twoE * sizeof(int));
    int*   perm    = (int*)alloc((size_t)n * sizeof(int));
    int*   hist    = (int*)alloc((size_t)NBUK * NBLK * sizeof(int));
    int*   bb      = (int*)alloc((size_t)(NBUK + 1) * sizeof(int));
    // pre aliases p01: written by k_scatter, read by k_place — both complete
    // before spmm<0> writes p01 (disjoint lifetimes, 12 MB < 77 MB).
    unsigned* pre  = (unsigned*)p01;
    (void)ws_size;

    // atomic-free CSR build (no memset needed anywhere)
    k_hist<<<NBLK, 256, 0, stream>>>(u_idx, i_idx, E, n_u, NBUK, hist);
    k_scanB<<<NBUK, 256, 0, stream>>>(hist, bb);
    k_scanT<<<1, 1024, 0, stream>>>(bb, NBUK);
    k_scatter<<<NBLK, 256, 0, stream>>>(u_idx, i_idx, E, n_u, NBUK, hist, bb, pre);
    k_place<<<NBUK, 256, 0, stream>>>(bb, n, n_u, pre, u_emb, i_emb,
                                      row_ptr, rnorm, adj, xq0, perm);

    int sblocks = (int)(((long long)n * 32 + 255) / 256);
    // layer 1: gathers fp8 xq0 -> writes fp8 xq1 (layer-2 table) + fp16 p01
    k_spmm<0><<<sblocks, 256, 0, stream>>>(row_ptr, adj, rnorm, perm, xq0, nullptr,
                                           u_emb, i_emb, n_u, n,
                                           nullptr, xq1, p01);
    // layer 2 + fused combine: out = (p01 + rnorm*(A @ S*rnorm.*x1)/S)/3
    k_spmm<1><<<sblocks, 256, 0, stream>>>(row_ptr, adj, rnorm, perm, xq1, p01,
                                           nullptr, nullptr, n_u, n,
                                           (float*)d_out, nullptr, nullptr);
}

// Round 13
// 320.698 us; speedup vs baseline: 1.0529x; 1.0529x over previous
//
#include <hip/hip_runtime.h>

#define DIM 128
#define NBLK 256        // edge-partition blocks for hist/scatter (must match)
#define BKT_BITS 9      // 512 rows per bucket
#define BKT_ROWS 512
#define MAXBUK 1024     // supports n up to 512K rows

#define S8   4096.0f            // fp8 table scale (2^12, exact)
#define INV8 (1.0f / 4096.0f)

using f16 = _Float16;
using f16x4 = __attribute__((ext_vector_type(4))) f16;
using f32x4 = __attribute__((ext_vector_type(4))) float;
using f32x2 = __attribute__((ext_vector_type(2))) float;

// ---------------- CSR build: atomic-free counting sort ----------------
// History: direct scatter = 16x write amplification (rounds 3-4). Global-atomic
// binning = atomic-latency-bound (rounds 5-6, ~5 atomics/us). This build has
// ZERO global atomics: positions precomputed by scans; stores fire-and-forget
// and temporally clustered per (block,bucket).
// Round 12 lesson: row-permutation (degree sort) in spmm REGRESSED — the
// indirection adds a dependent load to every row's chain and scrambles the
// contiguous row_ptr/rnorm/x0/p01 streams (lost prefetch, occupancy 75->65%).
// Rows must be processed in natural order.

// same-XCD blocks get adjacent output sub-ranges inside each bucket, so
// range-boundary cache lines are shared only within one XCD's L2
__device__ __forceinline__ int permb(int b) { return ((b & 7) << 5) | (b >> 3); }

// pass 1: per-block LDS histogram over 512-row buckets (both edge endpoints)
__global__ __launch_bounds__(256) void k_hist(const int* __restrict__ u_idx,
                                              const int* __restrict__ i_idx,
                                              int E, int n_u, int NBUK,
                                              int* __restrict__ hist) {
    __shared__ int h[MAXBUK];
    int b = blockIdx.x, tid = threadIdx.x;
    for (int j = tid; j < NBUK; j += 256) h[j] = 0;
    __syncthreads();
    int chunk = (E + NBLK - 1) / NBLK;
    int i0 = b * chunk, i1 = E < i0 + chunk ? E : i0 + chunk;
    for (int i = i0 + tid; i < i1; i += 256) {
        int u = __builtin_nontemporal_load(&u_idx[i]);
        int t = __builtin_nontemporal_load(&i_idx[i]) + n_u;
        atomicAdd(&h[u >> BKT_BITS], 1);
        atomicAdd(&h[t >> BKT_BITS], 1);
    }
    __syncthreads();
    int pb = permb(b);
    for (int j = tid; j < NBUK; j += 256) hist[j * NBLK + pb] = h[j];
}

// pass 2a: per-bucket exclusive scan over the 256 block counts (in place);
// bucket total goes to bb[k]
__global__ __launch_bounds__(256) void k_scanB(int* __restrict__ hist,
                                               int* __restrict__ bb) {
    __shared__ int sh[256];
    int k = blockIdx.x, t = threadIdx.x;
    int v = hist[k * NBLK + t];
    sh[t] = v;
    __syncthreads();
    for (int off = 1; off < 256; off <<= 1) {
        int tmp = (t >= off) ? sh[t - off] : 0;
        __syncthreads();
        sh[t] += tmp;
        __syncthreads();
    }
    hist[k * NBLK + t] = sh[t] - v;  // exclusive over (permuted) blocks
    if (t == 255) bb[k] = sh[255];   // bucket total
}

// pass 2b: exclusive scan of bucket totals -> bucket bases; bb[NBUK] = 2E
__global__ __launch_bounds__(1024) void k_scanT(int* __restrict__ bb, int NBUK) {
    __shared__ int sh[1024];
    int t = threadIdx.x;
    int v = (t < NBUK) ? bb[t] : 0;
    sh[t] = v;
    __syncthreads();
    for (int off = 1; off < 1024; off <<= 1) {
        int tmp = (t >= off) ? sh[t - off] : 0;
        __syncthreads();
        sh[t] += tmp;
        __syncthreads();
    }
    if (t < NBUK) bb[t] = sh[t] - v;
    if (t == NBUK - 1) bb[NBUK] = sh[t];
}

// pass 3: deterministic scatter into bucket-major pre[]. Entry = (c<<9 | r&511)
// (c < 2^19 ok for n=300K). Only LDS atomics (intra-block ranking); each
// (block,bucket) range ~80 B written back-to-back -> L2 write-combining.
__global__ __launch_bounds__(256) void k_scatter(const int* __restrict__ u_idx,
                                                 const int* __restrict__ i_idx,
                                                 int E, int n_u, int NBUK,
                                                 const int* __restrict__ hist,
                                                 const int* __restrict__ bb,
                                                 unsigned* __restrict__ pre) {
    __shared__ int boff[MAXBUK];
    __shared__ int cnt[MAXBUK];
    int b = blockIdx.x, tid = threadIdx.x;
    int pb = permb(b);
    for (int j = tid; j < NBUK; j += 256) {
        boff[j] = bb[j] + hist[j * NBLK + pb];
        cnt[j] = 0;
    }
    __syncthreads();
    int chunk = (E + NBLK - 1) / NBLK;
    int i0 = b * chunk, i1 = E < i0 + chunk ? E : i0 + chunk;
    for (int i = i0 + tid; i < i1; i += 256) {
        int u = __builtin_nontemporal_load(&u_idx[i]);
        int t = __builtin_nontemporal_load(&i_idx[i]) + n_u;
        int ku = u >> BKT_BITS, kt = t >> BKT_BITS;
        int p1 = atomicAdd(&cnt[ku], 1);
        pre[boff[ku] + p1] = ((unsigned)t << BKT_BITS) | (unsigned)(u & (BKT_ROWS - 1));
        int p2 = atomicAdd(&cnt[kt], 1);
        pre[boff[kt] + p2] = ((unsigned)u << BKT_BITS) | (unsigned)(t & (BKT_ROWS - 1));
    }
}

// pass 4: one block per bucket. Builds row_ptr + rnorm for its 512 rows from
// the bucket's own entries (LDS histogram + pair-scan), places into the
// bucket's contiguous ~20KB adj span (single-XCD L2-hot), then — fused —
// encodes the fp8 gather table for its own rows:
//   xq0[v] = fp8( S8 * rnorm[v] * x0[v] )     (128 B/row, e4m3, scale 2^12)
// fp8 is safe HERE because xq0 feeds only the gather-SUM path (errors average
// down over deg terms); epilogue identity terms use exact fp32/fp16 paths.
__global__ __launch_bounds__(256) void k_place(const int* __restrict__ bb, int n, int n_u,
                                               const unsigned* __restrict__ pre,
                                               const float* __restrict__ u_emb,
                                               const float* __restrict__ i_emb,
                                               int* __restrict__ row_ptr,
                                               float* __restrict__ rnorm,
                                               int* __restrict__ adj,
                                               unsigned* __restrict__ xq0) {
    __shared__ int cnt[BKT_ROWS];
    __shared__ int cur[BKT_ROWS];
    __shared__ int ps[256];
    int b = blockIdx.x, t = threadIdx.x;
    int r0 = b << BKT_BITS;
    int base = bb[b], end = bb[b + 1];
    cnt[t] = 0;
    cnt[t + 256] = 0;
    __syncthreads();
    for (int i = base + t; i < end; i += 256)
        atomicAdd(&cnt[pre[i] & (BKT_ROWS - 1)], 1);
    __syncthreads();
    // exclusive scan over 512 rows via pair-sums (256-wide Hillis-Steele)
    int a0 = cnt[2 * t], a1 = cnt[2 * t + 1];
    int pv = a0 + a1;
    ps[t] = pv;
    __syncthreads();
    for (int off = 1; off < 256; off <<= 1) {
        int tmp = (t >= off) ? ps[t - off] : 0;
        __syncthreads();
        ps[t] += tmp;
        __syncthreads();
    }
    int ex = ps[t] - pv;        // elems before row 2t
    int e0 = base + ex;         // start of row 2t
    int e1 = e0 + a0;           // start of row 2t+1
    cur[2 * t] = e0;
    cur[2 * t + 1] = e1;
    int rows = n - r0; if (rows > BKT_ROWS) rows = BKT_ROWS;
    if (2 * t < rows) {
        row_ptr[r0 + 2 * t] = e0;
        rnorm[r0 + 2 * t] = (a0 > 0) ? rsqrtf(2.0f * (float)a0) : 0.0f;
    }
    if (2 * t + 1 < rows) {
        row_ptr[r0 + 2 * t + 1] = e1;
        rnorm[r0 + 2 * t + 1] = (a1 > 0) ? rsqrtf(2.0f * (float)a1) : 0.0f;
    }
    if (t == 0 && r0 + BKT_ROWS >= n) row_ptr[n] = end;
    __syncthreads();
    for (int i = base + t; i < end; i += 256) {
        unsigned p = pre[i];  // L2-hot from k_scatter
        int rl = (int)(p & (BKT_ROWS - 1));
        int c = (int)(p >> BKT_BITS);
        int pos = atomicAdd(&cur[rl], 1);
        adj[pos] = c;
    }
    // fused fp8-encode epilogue (uses cnt[], untouched after histogram)
    for (int g = t; g < rows * 32; g += 256) {
        int vr = g >> 5;
        int lane = g & 31;
        int v = r0 + vr;
        int d = cnt[vr];
        float r = (d > 0) ? rsqrtf(2.0f * (float)d) : 0.0f;
        float sr = r * S8;
        const float* src = (v < n_u) ? (u_emb + (size_t)v * DIM)
                                     : (i_emb + (size_t)(v - n_u) * DIM);
        f32x4 x = __builtin_nontemporal_load(
            reinterpret_cast<const f32x4*>(src + lane * 4));
        int q = __builtin_amdgcn_cvt_pk_fp8_f32(x[0] * sr, x[1] * sr, 0, false);
        q = __builtin_amdgcn_cvt_pk_fp8_f32(x[2] * sr, x[3] * sr, q, true);
        xq0[(size_t)v * 32 + lane] = (unsigned)q;
    }
}

// ---------------- SpMM ----------------
// One 32-lane half-wave per row (natural row order — see round-12 lesson);
// 4 fp8 elements (4B uint) per lane.
// Gather tables are fp8, pre-scaled by S8*rnorm[c] (weights folded).
// 8-wide issue block: all 8 gathers in flight before any decode (r11:
// latency/concurrency-bound regime; this was the last measurable win).
// MODE 0: gathers xq0; acc = S8 * x1[row]/rnorm[row]. Writes:
//   xq1[row] = fp8(rnr^2 * acc),  p01[row] = fp16(x0 + rnr*acc/S8).
// MODE 1: gathers xq1; out = (p01[row] + rnr*acc/S8) / 3.  y store NT.

#define DECODE_ACC(Q)                                                     \
    {                                                                     \
        f32x2 lo_ = __builtin_amdgcn_cvt_pk_f32_fp8((int)(Q), false);     \
        f32x2 hi_ = __builtin_amdgcn_cvt_pk_f32_fp8((int)(Q), true);      \
        acc[0] += lo_[0]; acc[1] += lo_[1];                               \
        acc[2] += hi_[0]; acc[3] += hi_[1];                               \
    }

template <int MODE>
__global__ __launch_bounds__(256) void k_spmm(const int* __restrict__ row_ptr,
                                              const int* __restrict__ adj,
                                              const float* __restrict__ rnorm,
                                              const unsigned* __restrict__ xq,
                                              const f16* __restrict__ p01,
                                              const float* __restrict__ u_emb,
                                              const float* __restrict__ i_emb,
                                              int n_u, int n,
                                              float* __restrict__ y,
                                              unsigned* __restrict__ xq1o,
                                              f16* __restrict__ p01o) {
    int g = blockIdx.x * blockDim.x + threadIdx.x;
    int row = g >> 5;
    int lane = g & 31;
    if (row >= n) return;
    int s = row_ptr[row];
    int e = row_ptr[row + 1];
    float rnr = rnorm[row];

    // hoisted epilogue stream loads (latency hides under the gather loop)
    f32x4 x0;
    f16x4 p;
    if (MODE == 0) {
        const float* x0b = (row < n_u) ? (u_emb + (size_t)row * DIM)
                                       : (i_emb + (size_t)(row - n_u) * DIM);
        x0 = __builtin_nontemporal_load(
            reinterpret_cast<const f32x4*>(x0b + lane * 4));
    } else {
        p = __builtin_nontemporal_load(
            reinterpret_cast<const f16x4*>(p01 + (size_t)row * DIM + lane * 4));
    }

    f32x4 acc = {0.f, 0.f, 0.f, 0.f};
    const unsigned* xb = xq + lane;
    int k = s;
    // 8-wide issue block: all 8 gathers in flight before any decode
    for (; k + 8 <= e; k += 8) {
        int c0 = adj[k + 0], c1 = adj[k + 1], c2 = adj[k + 2], c3 = adj[k + 3];
        int c4 = adj[k + 4], c5 = adj[k + 5], c6 = adj[k + 6], c7 = adj[k + 7];
        unsigned q0 = xb[(size_t)c0 * 32];
        unsigned q1 = xb[(size_t)c1 * 32];
        unsigned q2 = xb[(size_t)c2 * 32];
        unsigned q3 = xb[(size_t)c3 * 32];
        unsigned q4 = xb[(size_t)c4 * 32];
        unsigned q5 = xb[(size_t)c5 * 32];
        unsigned q6 = xb[(size_t)c6 * 32];
        unsigned q7 = xb[(size_t)c7 * 32];
        DECODE_ACC(q0) DECODE_ACC(q1) DECODE_ACC(q2) DECODE_ACC(q3)
        DECODE_ACC(q4) DECODE_ACC(q5) DECODE_ACC(q6) DECODE_ACC(q7)
    }
    // 4-wide block
    if (k + 4 <= e) {
        int c0 = adj[k + 0], c1 = adj[k + 1], c2 = adj[k + 2], c3 = adj[k + 3];
        unsigned q0 = xb[(size_t)c0 * 32];
        unsigned q1 = xb[(size_t)c1 * 32];
        unsigned q2 = xb[(size_t)c2 * 32];
        unsigned q3 = xb[(size_t)c3 * 32];
        DECODE_ACC(q0) DECODE_ACC(q1) DECODE_ACC(q2) DECODE_ACC(q3)
        k += 4;
    }
    // scalar tail (0-3)
    for (; k < e; ++k) {
        int c = adj[k];
        unsigned q = xb[(size_t)c * 32];
        DECODE_ACC(q)
    }

    if (MODE == 0) {
        // layer-2 gather table: fp8(S8 * rnorm * x1) = fp8(rnr^2 * acc)
        float sc = rnr * rnr;
        int q = __builtin_amdgcn_cvt_pk_fp8_f32(acc[0] * sc, acc[1] * sc, 0, false);
        q = __builtin_amdgcn_cvt_pk_fp8_f32(acc[2] * sc, acc[3] * sc, q, true);
        xq1o[(size_t)row * 32 + lane] = (unsigned)q;
        // epilogue operand: fp16(x0 + x1), exact x0 from emb (hoisted load)
        float t1 = rnr * INV8;  // x1 = acc * rnr / S8
        f16x4 po;
        po[0] = (f16)(x0[0] + acc[0] * t1);
        po[1] = (f16)(x0[1] + acc[1] * t1);
        po[2] = (f16)(x0[2] + acc[2] * t1);
        po[3] = (f16)(x0[3] + acc[3] * t1);
        *reinterpret_cast<f16x4*>(p01o + (size_t)row * DIM + lane * 4) = po;
    } else {
        const float third = 1.0f / 3.0f;
        float t2 = rnr * INV8;  // x2 = acc * rnr / S8
        f32x4 o;
        o[0] = ((float)p[0] + acc[0] * t2) * third;
        o[1] = ((float)p[1] + acc[1] * t2) * third;
        o[2] = ((float)p[2] + acc[2] * t2) * third;
        o[3] = ((float)p[3] + acc[3] * t2) * third;
        __builtin_nontemporal_store(
            o, reinterpret_cast<f32x4*>(y + (size_t)row * DIM + lane * 4));
    }
}

// ---------------- host ----------------

extern "C" void kernel_launch(void* const* d_in, const int* in_sizes, int n_in,
                              void* d_out, int out_size, void* d_ws, size_t ws_size,
                              hipStream_t stream) {
    const float* u_emb = (const float*)d_in[0];
    const float* i_emb = (const float*)d_in[1];
    const int* u_idx = (const int*)d_in[2];
    const int* i_idx = (const int*)d_in[3];

    const int n_u = in_sizes[0] / DIM;
    const int n_i = in_sizes[1] / DIM;
    const int n = n_u + n_i;
    const int E = in_sizes[2];
    const int twoE = 2 * E;
    const int NBUK = (n + BKT_ROWS - 1) >> BKT_BITS;  // <= MAXBUK for n <= 512K

    // workspace layout
    char* w = (char*)d_ws;
    auto alloc = [&](size_t bytes) -> void* {
        void* p = (void*)w;
        w += (bytes + 255) & ~(size_t)255;
        return p;
    };
    unsigned* xq0   = (unsigned*)alloc((size_t)n * 32 * sizeof(unsigned)); // fp8 S*rnorm*x0
    unsigned* xq1   = (unsigned*)alloc((size_t)n * 32 * sizeof(unsigned)); // fp8 S*rnorm*x1
    f16*   p01     = (f16*)alloc((size_t)n * DIM * sizeof(f16));          // fp16 x0+x1
    float* rnorm   = (float*)alloc((size_t)n * sizeof(float));
    int*   row_ptr = (int*)alloc((size_t)(n + 1) * sizeof(int));
    int*   adj     = (int*)alloc((size_t)twoE * sizeof(int));
    int*   hist    = (int*)alloc((size_t)NBUK * NBLK * sizeof(int));
    int*   bb      = (int*)alloc((size_t)(NBUK + 1) * sizeof(int));
    // pre aliases p01: written by k_scatter, read by k_place — both complete
    // before spmm<0> writes p01 (disjoint lifetimes, 12 MB < 77 MB).
    unsigned* pre  = (unsigned*)p01;
    (void)ws_size;

    // atomic-free CSR build (no memset needed anywhere)
    k_hist<<<NBLK, 256, 0, stream>>>(u_idx, i_idx, E, n_u, NBUK, hist);
    k_scanB<<<NBUK, 256, 0, stream>>>(hist, bb);
    k_scanT<<<1, 1024, 0, stream>>>(bb, NBUK);
    k_scatter<<<NBLK, 256, 0, stream>>>(u_idx, i_idx, E, n_u, NBUK, hist, bb, pre);
    k_place<<<NBUK, 256, 0, stream>>>(bb, n, n_u, pre, u_emb, i_emb,
                                      row_ptr, rnorm, adj, xq0);

    int sblocks = (int)(((long long)n * 32 + 255) / 256);
    // layer 1: gathers fp8 xq0 -> writes fp8 xq1 (layer-2 table) + fp16 p01
    k_spmm<0><<<sblocks, 256, 0, stream>>>(row_ptr, adj, rnorm, xq0, nullptr,
                                           u_emb, i_emb, n_u, n,
                                           nullptr, xq1, p01);
    // layer 2 + fused combine: out = (p01 + rnorm*(A @ S*rnorm.*x1)/S)/3
    k_spmm<1><<<sblocks, 256, 0, stream>>>(row_ptr, adj, rnorm, xq1, p01,
                                           nullptr, nullptr, n_u, n,
                                           (float*)d_out, nullptr, nullptr);
}